// Round 3
// baseline (278.338 us; speedup 1.0000x reference)
//
#include <hip/hip_runtime.h>
#include <math.h>

#define NTOK 197
#define BATCH 8
#define QKSCALE 0.17677669529663687f  /* 32^-0.5 */

typedef float f32x4 __attribute__((ext_vector_type(4)));
typedef short bf16x8 __attribute__((ext_vector_type(8)));

union U4S8 { uint4 u4; unsigned u[4]; bf16x8 s; };

// pack two f32 -> packed bf16x2 (RNE) via HW cvt_pk
__device__ inline unsigned pack2(float lo, float hi) {
  unsigned r;
  asm("v_cvt_pk_bf16_f32 %0, %1, %2" : "=v"(r) : "v"(lo), "v"(hi));
  return r;
}

// unpack 2 bf16 from u32, multiply by s, repack
__device__ inline unsigned mulpack(unsigned v, float s) {
  float lo = __uint_as_float(v << 16) * s;
  float hi = __uint_as_float(v & 0xffff0000u) * s;
  return pack2(lo, hi);
}

// ---------------------------------------------------------------------------
// Kernel A (fused k0+k1): blocks [0,NU) transpose unique_params f32[u][d][e]
// -> bf16 wt[u][e][d]; blocks [NU, NU+394) do LayerNorm + QK projection
// (4 rows per block, one wave each). Block 0 also zeroes the split-K counters.
// ---------------------------------------------------------------------------
__global__ __launch_bounds__(256) void kA(
    const float* __restrict__ up, const float* __restrict__ x,
    const float* __restrict__ gamma, const float* __restrict__ beta,
    const float* __restrict__ wqk, unsigned short* __restrict__ wt,
    unsigned short* __restrict__ xnb, float* __restrict__ q,
    float* __restrict__ k, int* __restrict__ cnt, int NU) {
  int bid = blockIdx.x;
  int t = threadIdx.x;
  if (bid == 0 && t < NTOK) cnt[t] = 0;

  if (bid < NU) {
    // ---- transpose + bf16 convert ----
    int u = bid;
    int e = t >> 2, dg = t & 3;
    const float* src = up + (size_t)u * 4096 + dg * 16 * 64 + e;
    unsigned o[8];
    #pragma unroll
    for (int j = 0; j < 8; ++j) {
      float f0 = src[(2 * j) * 64];
      float f1 = src[(2 * j + 1) * 64];
      o[j] = pack2(f0, f1);
    }
    unsigned short* dst = wt + (size_t)u * 4096 + e * 64 + dg * 16;
    *(uint4*)dst = make_uint4(o[0], o[1], o[2], o[3]);
    *(uint4*)(dst + 8) = make_uint4(o[4], o[5], o[6], o[7]);
    return;
  }

  // ---- LayerNorm + QK: row = (bid-NU)*4 + wave ----
  int w = t >> 6, d = t & 63;
  int row = (bid - NU) * 4 + w;      // b*NTOK + n, 0..1575
  int b = row / NTOK, n = row % NTOK;

  float v = x[(size_t)row * 64 + d];
  float s = v, s2 = v * v;
  #pragma unroll
  for (int off = 32; off; off >>= 1) {
    s  += __shfl_xor(s, off);
    s2 += __shfl_xor(s2, off);
  }
  float mu  = s * (1.0f / 64.0f);
  float var = s2 * (1.0f / 64.0f) - mu * mu;
  float rr  = rsqrtf(var + 1e-5f);
  float xv  = (v - mu) * rr * gamma[d] + beta[d];

  unsigned ub = __float_as_uint(xv);
  ub += 0x7fff + ((ub >> 16) & 1);
  xnb[(size_t)(n * BATCH + b) * 64 + d] = (unsigned short)(ub >> 16);

  __shared__ float xs[4][64];
  xs[w][d] = xv;                     // same-wave RAW, no barrier needed

  float a0 = 0.f, a1 = 0.f;
  #pragma unroll 8
  for (int dd = 0; dd < 64; ++dd) {
    float xr = xs[w][dd];
    a0 = fmaf(xr, wqk[dd * 128 + d], a0);
    a1 = fmaf(xr, wqk[dd * 128 + 64 + d], a1);
  }
  int h = d >> 5, d32 = d & 31;
  int bh = h * BATCH + b;
  q[((size_t)bh * NTOK + n) * 32 + d32] = a0 * QKSCALE;
  k[((size_t)bh * NTOK + n) * 32 + d32] = a1;
}

// ---------------------------------------------------------------------------
// Kernel 2: dots + softmax. grid = 16*N blocks, 256 thr.
// attn written as [n][m][bh] (16 f32 per (n,m), for k3's broadcast reads).
// ---------------------------------------------------------------------------
__global__ __launch_bounds__(256) void k2_attn(
    const float* __restrict__ q, const float* __restrict__ k,
    float* __restrict__ attn) {
  int id = blockIdx.x;             // bh*NTOK + n
  int bh = id / NTOK, n = id % NTOK;
  int t = threadIdx.x;

  __shared__ float qs[32];
  __shared__ float redmx[4];
  __shared__ float redsm[4];
  if (t < 32) qs[t] = q[((size_t)bh * NTOK + n) * 32 + t];
  __syncthreads();

  int m = t;
  float sdot = -3.0e38f;
  if (m < NTOK) {
    const float4* kr = (const float4*)&k[((size_t)bh * NTOK + m) * 32];
    const float4* qr = (const float4*)qs;
    float acc = 0.f;
    #pragma unroll
    for (int i = 0; i < 8; ++i) {
      float4 kv = kr[i], qv = qr[i];
      acc = fmaf(kv.x, qv.x, acc);
      acc = fmaf(kv.y, qv.y, acc);
      acc = fmaf(kv.z, qv.z, acc);
      acc = fmaf(kv.w, qv.w, acc);
    }
    sdot = acc;
  }
  float mx = sdot;
  #pragma unroll
  for (int off = 32; off; off >>= 1) mx = fmaxf(mx, __shfl_xor(mx, off));
  int wid = t >> 6;
  if ((t & 63) == 0) redmx[wid] = mx;
  __syncthreads();
  mx = fmaxf(fmaxf(redmx[0], redmx[1]), fmaxf(redmx[2], redmx[3]));

  float p = (m < NTOK) ? __expf(sdot - mx) : 0.f;
  float sm = p;
  #pragma unroll
  for (int off = 32; off; off >>= 1) sm += __shfl_xor(sm, off);
  if ((t & 63) == 0) redsm[wid] = sm;
  __syncthreads();
  sm = (redsm[0] + redsm[1]) + (redsm[2] + redsm[3]);

  if (m < NTOK) attn[((size_t)n * NTOK + m) * 16 + bh] = p / sm;
}

// ---------------------------------------------------------------------------
// Kernel 3: main einsum via MFMA + fused split-K combine + output projection.
// grid = 1576 = 8 XCD x 197; block (n, s in [0,8)); 4 waves, wave w owns
// split si = s*4+w of 32. Software-pipelined: double-buffered B-fragments in
// registers, A/imap prefetched. Waves combine via LDS -> part slot s; last
// block per n (atomic counter) sums 8 slots and applies W_out + bias.
// ---------------------------------------------------------------------------
__global__ __launch_bounds__(256, 4) void k3_main(
    const unsigned short* __restrict__ xnb, const float* __restrict__ attn,
    const unsigned short* __restrict__ wt, const int* __restrict__ imap,
    float* __restrict__ part, int* __restrict__ cnt,
    const float* __restrict__ wout, const float* __restrict__ bout,
    float* __restrict__ out) {
  int bid = blockIdx.x;
  // bijective XCD swizzle: 1576 = 8*197, each XCD gets a contiguous n-range
  int swz = (bid & 7) * 197 + (bid >> 3);
  int n = swz >> 3, s = swz & 7;
  int w = threadIdx.x >> 6, lane = threadIdx.x & 63;
  int si = s * 4 + w;
  int m0 = (NTOK * si) / 32, m1 = (NTOK * (si + 1)) / 32;

  int r = lane & 15;               // A row = h*8+b ; also B col index (e)
  int g = lane >> 4;               // k-subgroup
  int b = r & 7;

  f32x4 acc[4];
  #pragma unroll
  for (int t4 = 0; t4 < 4; ++t4) acc[t4] = (f32x4)0.0f;

  const unsigned short* xbase = xnb + b * 64 + 8 * g;
  const int* im = imap + n * NTOK;

  U4S8 Ba[4][2], Bb[4][2];
  uint4 xa0, xa1, xb0, xb1;
  float aa, ab;

  auto issueB = [&](U4S8 (&bf)[4][2], int u) {
    const unsigned short* wp = wt + (size_t)u * 4096 + r * 64 + 8 * g;
    #pragma unroll
    for (int t4 = 0; t4 < 4; ++t4) {
      bf[t4][0].s = *(const bf16x8*)(wp + t4 * 1024);
      bf[t4][1].s = *(const bf16x8*)(wp + t4 * 1024 + 32);
    }
  };
  auto loadA = [&](int m, uint4& v0, uint4& v1, float& av) {
    v0 = *(const uint4*)(xbase + (size_t)m * 512);
    v1 = *(const uint4*)(xbase + (size_t)m * 512 + 32);
    av = attn[((size_t)n * NTOK + m) * 16 + r];
  };
  auto compute = [&](U4S8 (&bf)[4][2], uint4 v0, uint4 v1, float av) {
    U4S8 a0, a1;
    #pragma unroll
    for (int qd = 0; qd < 4; ++qd) {
      a0.u[qd] = mulpack(((const unsigned*)&v0)[qd], av);
      a1.u[qd] = mulpack(((const unsigned*)&v1)[qd], av);
    }
    #pragma unroll
    for (int t4 = 0; t4 < 4; ++t4) {
      acc[t4] = __builtin_amdgcn_mfma_f32_16x16x32_bf16(a0.s, bf[t4][0].s, acc[t4], 0, 0, 0);
      acc[t4] = __builtin_amdgcn_mfma_f32_16x16x32_bf16(a1.s, bf[t4][1].s, acc[t4], 0, 0, 0);
    }
  };

  // prologue
  int u1 = im[m0];                                   // u(m0) -> issue now
  issueB(Ba, u1);
  loadA(m0, xa0, xa1, aa);
  u1 = (m0 + 1 < m1) ? im[m0 + 1] : 0;               // u(m+1)
  int u2 = (m0 + 2 < m1) ? im[m0 + 2] : 0;           // u(m+2)

  int m = m0;
  while (1) {
    // phase A: current = Ba/xa
    {
      bool hn = (m + 1 < m1);
      if (hn) { issueB(Bb, u1); loadA(m + 1, xb0, xb1, ab); }
      int u3 = (m + 3 < m1) ? im[m + 3] : 0;
      compute(Ba, xa0, xa1, aa);
      ++m;
      if (!hn) break;
      u1 = u2; u2 = u3;
    }
    // phase B: current = Bb/xb
    {
      bool hn = (m + 1 < m1);
      if (hn) { issueB(Ba, u1); loadA(m + 1, xa0, xa1, aa); }
      int u3 = (m + 3 < m1) ? im[m + 3] : 0;
      compute(Bb, xb0, xb1, ab);
      ++m;
      if (!hn) break;
      u1 = u2; u2 = u3;
    }
  }

  // ---- wave tiles -> LDS, combine 4 waves -> part slot s ----
  __shared__ float pbuf[4][512];
  int c = lane & 15;
  int hb = 4 * (g & 1);
  #pragma unroll
  for (int t4 = 0; t4 < 4; ++t4) {
    if ((g >> 1) == (t4 >> 1)) {
      #pragma unroll
      for (int reg = 0; reg < 4; ++reg)
        pbuf[w][(hb + reg) * 64 + 16 * t4 + c] = acc[t4][reg];
    }
  }
  __syncthreads();
  int t = threadIdx.x;
  float* po = part + ((size_t)s * NTOK + n) * 512;
  #pragma unroll
  for (int i = t; i < 512; i += 256)
    po[i] = (pbuf[0][i] + pbuf[1][i]) + (pbuf[2][i] + pbuf[3][i]);

  // ---- split-K last-block combine + output projection ----
  __threadfence();
  __syncthreads();
  __shared__ int lastS;
  if (t == 0) lastS = (atomicAdd(&cnt[n], 1) == 7);
  __syncthreads();
  if (!lastS) return;
  __threadfence();

  float* isb = pbuf[0];            // reuse LDS
  #pragma unroll
  for (int i = t; i < 512; i += 256) {
    float a2 = 0.f;
    #pragma unroll
    for (int p = 0; p < 8; ++p)
      a2 += part[((size_t)p * NTOK + n) * 512 + i];
    isb[i] = a2;
  }
  __syncthreads();
  #pragma unroll
  for (int i = t; i < 512; i += 256) {
    int bb = i >> 6, dc = i & 63;
    float o = bout[dc];
    const float* ir = isb + bb * 64;
    #pragma unroll 8
    for (int ee = 0; ee < 64; ++ee)
      o = fmaf(ir[ee], wout[ee * 64 + dc], o);
    out[((size_t)bb * NTOK + n) * 64 + dc] = o;
  }
}

// ---------------------------------------------------------------------------
extern "C" void kernel_launch(void* const* d_in, const int* in_sizes, int n_in,
                              void* d_out, int out_size, void* d_ws, size_t ws_size,
                              hipStream_t stream) {
  const float* x     = (const float*)d_in[0];
  const float* gamma = (const float*)d_in[1];
  const float* beta  = (const float*)d_in[2];
  const float* wqk   = (const float*)d_in[3];
  const float* up    = (const float*)d_in[4];
  const float* wout  = (const float*)d_in[5];
  const float* bout  = (const float*)d_in[6];
  const int*   imap  = (const int*)d_in[7];
  float* out = (float*)d_out;

  int NU = in_sizes[4] / 4096;     // 1122 unique 64x64 matrices

  // workspace layout (bytes)
  char* w8 = (char*)d_ws;
  unsigned short* wtb = (unsigned short*)w8;                 // NU*4096*2      = 9,191,424
  unsigned short* xnb = (unsigned short*)(w8 + 9191424);     // 197*8*64*2     =   201,728
  float* q    = (float*)(w8 + 9393152);                      // 16*197*32*4    =   403,456
  float* kk   = (float*)(w8 + 9796608);                      // 16*197*32*4    =   403,456
  float* attn = (float*)(w8 + 10200064);                     // 197*197*16*4   = 2,483,776
  float* part = (float*)(w8 + 12683840);                     // 8*197*512*4    = 3,227,648
  int*   cnt  = (int*)  (w8 + 15911488);                     // 197*4
                                                             // total ~15.9 MB

  kA      <<<NU + 394,    256, 0, stream>>>(up, x, gamma, beta, wqk, wtb, xnb, q, kk, cnt, NU);
  k2_attn <<<16 * NTOK,   256, 0, stream>>>(q, kk, attn);
  k3_main <<<8 * NTOK,    256, 0, stream>>>(xnb, attn, wtb, imap, part, cnt, wout, bout, out);
}

// Round 5
// 132.136 us; speedup vs baseline: 2.1065x; 2.1065x over previous
//
#include <hip/hip_runtime.h>
#include <math.h>

#define NTOK 197
#define QKSCALE 0.17677669529663687f  /* 32^-0.5 */
#define DYNLDS 142336                 /* 114688 W + 14336 xn + 13312 attn(pad) */

typedef float f32x4 __attribute__((ext_vector_type(4)));
typedef short bf16x8 __attribute__((ext_vector_type(8)));
union U4S8 { uint4 u4; unsigned u[4]; bf16x8 s; };

__device__ inline unsigned pack2(float lo, float hi) {
  unsigned r;
  asm("v_cvt_pk_bf16_f32 %0, %1, %2" : "=v"(r) : "v"(lo), "v"(hi));
  return r;
}
// unpack 2 bf16 from u32, multiply by s (f32), repack to bf16x2
__device__ inline unsigned mulpack(unsigned v, float s) {
  float lo = __uint_as_float(v << 16) * s;
  float hi = __uint_as_float(v & 0xffff0000u) * s;
  return pack2(lo, hi);
}
__device__ inline void gl_lds16(const void* g, void* l) {
  __builtin_amdgcn_global_load_lds(
      (const __attribute__((address_space(1))) unsigned int*)g,
      (__attribute__((address_space(3))) unsigned int*)l, 16, 0, 0);
}
#define MFMA __builtin_amdgcn_mfma_f32_16x16x32_bf16

// ---------------------------------------------------------------------------
// Kernel A: blocks [0,NU): transpose+convert unique_params -> wt2 (bf16,
// MFMA-fragment-linear layout: 16B unit U=((t*2+s)*64+g*16+r) holds
// W[d=32s+8g+j][e=16t+r], j=0..7). Blocks [NU,NU+394): LayerNorm + QK proj.
// ---------------------------------------------------------------------------
__global__ __launch_bounds__(256) void kA(
    const float* __restrict__ up, const float* __restrict__ x,
    const float* __restrict__ gamma, const float* __restrict__ beta,
    const float* __restrict__ wqk, unsigned short* __restrict__ wt2,
    unsigned short* __restrict__ xnb, float* __restrict__ q,
    float* __restrict__ k, int NU) {
  int bid = blockIdx.x, t = threadIdx.x;
  if (bid < NU) {
    __shared__ unsigned short tr[4096];
    const float4* src = (const float4*)(up + (size_t)bid * 4096);
    #pragma unroll
    for (int kk2 = 0; kk2 < 4; ++kk2) {
      int i = t + kk2 * 256;
      float4 v = src[i];
      int d = i >> 4, e0 = (i & 15) * 4;
      float vv[4] = {v.x, v.y, v.z, v.w};
      #pragma unroll
      for (int c = 0; c < 4; ++c) {
        int e = e0 + c;
        unsigned ub = __float_as_uint(vv[c]);
        ub += 0x7fff + ((ub >> 16) & 1);
        int U = ((e >> 4) * 2 + (d >> 5)) * 64 + ((d >> 3) & 3) * 16 + (e & 15);
        tr[U * 8 + (d & 7)] = (unsigned short)(ub >> 16);
      }
    }
    __syncthreads();
    uint4* dst = (uint4*)(wt2 + (size_t)bid * 4096);
    const uint4* s4 = (const uint4*)tr;
    dst[2 * t] = s4[2 * t];
    dst[2 * t + 1] = s4[2 * t + 1];
    return;
  }
  // ---- LayerNorm + QK: row = (bid-NU)*4 + wave ----
  int w = t >> 6, d = t & 63;
  int row = (bid - NU) * 4 + w;      // b*NTOK + n
  int b = row / NTOK, n = row % NTOK;

  float v = x[(size_t)row * 64 + d];
  float s = v, s2 = v * v;
  #pragma unroll
  for (int off = 32; off; off >>= 1) {
    s  += __shfl_xor(s, off);
    s2 += __shfl_xor(s2, off);
  }
  float mu  = s * (1.0f / 64.0f);
  float var = s2 * (1.0f / 64.0f) - mu * mu;
  float rr  = rsqrtf(var + 1e-5f);
  float xv  = (v - mu) * rr * gamma[d] + beta[d];

  unsigned ub = __float_as_uint(xv);
  ub += 0x7fff + ((ub >> 16) & 1);
  xnb[(size_t)(n * 8 + b) * 64 + d] = (unsigned short)(ub >> 16);

  __shared__ float xs[4][64];
  xs[w][d] = xv;                     // same-wave RAW

  float a0 = 0.f, a1 = 0.f;
  #pragma unroll 8
  for (int dd = 0; dd < 64; ++dd) {
    float xr = xs[w][dd];
    a0 = fmaf(xr, wqk[dd * 128 + d], a0);
    a1 = fmaf(xr, wqk[dd * 128 + 64 + d], a1);
  }
  int h = d >> 5, d32 = d & 31;
  int bh = h * 8 + b;
  q[((size_t)bh * NTOK + n) * 32 + d32] = a0 * QKSCALE;
  k[((size_t)bh * NTOK + n) * 32 + d32] = a1;
}

// ---------------------------------------------------------------------------
// Kernel 2: dots + softmax. grid = 256 (bh 16 x chunk 16); K staged in LDS
// transposed [dd][m] pad-201 (conflict-free both sides); each wave owns
// 3-4 full n-rows -> no block-reduce, no per-n barriers.
// attn written [n][m][16].
// ---------------------------------------------------------------------------
__global__ __launch_bounds__(256) void k2_attn(
    const float* __restrict__ q, const float* __restrict__ kk,
    float* __restrict__ attn) {
  int bh = blockIdx.x >> 4, ch = blockIdx.x & 15;
  int n0 = ch * 12 + (ch < 5 ? ch : 5);
  int len = (ch < 5) ? 13 : 12;
  int t = threadIdx.x, w = t >> 6, lane = t & 63;
  __shared__ float ks2[32 * 201];
  __shared__ float qsl[13 * 32];
  const float* kbase = kk + (size_t)bh * NTOK * 32;
  for (int i = t; i < NTOK * 32; i += 256) {
    int m = i >> 5, dd = i & 31;
    ks2[dd * 201 + m] = kbase[i];
  }
  for (int i = t; i < len * 32; i += 256)
    qsl[i] = q[((size_t)bh * NTOK + n0) * 32 + i];
  __syncthreads();

  for (int ni = w; ni < len; ni += 4) {
    int n = n0 + ni;
    float dots[4];
    #pragma unroll
    for (int p = 0; p < 4; ++p) {
      int m = lane + p * 64;
      float a = -3.0e38f;
      if (m < NTOK) {
        a = 0.f;
        #pragma unroll 8
        for (int dd = 0; dd < 32; ++dd)
          a = fmaf(ks2[dd * 201 + m], qsl[ni * 32 + dd], a);
      }
      dots[p] = a;
    }
    float mx = fmaxf(fmaxf(dots[0], dots[1]), fmaxf(dots[2], dots[3]));
    #pragma unroll
    for (int off = 32; off; off >>= 1) mx = fmaxf(mx, __shfl_xor(mx, off));
    float ps[4], sm = 0.f;
    #pragma unroll
    for (int p = 0; p < 4; ++p) {
      ps[p] = (lane + p * 64 < NTOK) ? __expf(dots[p] - mx) : 0.f;
      sm += ps[p];
    }
    #pragma unroll
    for (int off = 32; off; off >>= 1) sm += __shfl_xor(sm, off);
    float inv = 1.0f / sm;
    #pragma unroll
    for (int p = 0; p < 4; ++p) {
      int m = lane + p * 64;
      if (m < NTOK) attn[((size_t)n * NTOK + m) * 16 + bh] = ps[p] * inv;
    }
  }
}

// ---------------------------------------------------------------------------
// Kernel 3: main einsum via MFMA.
//  blocks [0,392): image pairs. block=(x_q,x_m,dhalf): 13-14 W tiles (closed
//   form u = dx*27+dy, contiguous!) staged in LDS via global_load_lds; xn
//   (XOR-swizzled) + attn staged too. Wave owns queries yq = w+4*qi (acc in
//   regs, static unroll); ym-loop reads W frags from LDS (contiguous 1KB
//   ds_read_b128), builds A = bf16(attn*xn), 8 MFMA/pair. Writes valid-half
//   tile to part slot (x_m*2+dh).
//  blocks [392,400): CLS query row (n=0), m-split streaming, u=729+m.
//  blocks [400,414): m=0 column, u=925+n, per-query streaming, slot 28.
// ---------------------------------------------------------------------------
__global__ __launch_bounds__(256, 1) void k3_main(
    const unsigned short* __restrict__ xnb, const float* __restrict__ attnp,
    const unsigned short* __restrict__ wt2, float* __restrict__ part,
    float* __restrict__ cls_part) {
  extern __shared__ char lds[];
  int bid = blockIdx.x, t = threadIdx.x, w = t >> 6, lane = t & 63;
  int r = lane & 15, g = lane >> 4, b = r & 7;

  if (bid < 392) {
    int swz = (bid & 7) * 49 + (bid >> 3);   // bijective XCD swizzle (392=8*49)
    int xq = swz / 28, rem = swz - xq * 28;
    int xm = rem >> 1, dh = rem & 1;
    int ntile = 14 - dh;
    int dx = xq - xm + 13;
    int ubase = dx * 27 + dh * 14;
    int m0tok = 1 + 14 * xm, nq0 = 1 + 14 * xq;

    // ---- stage W tiles (linear), xn (swizzled src), attn (linear) ----
    const char* wsrc = (const char*)(wt2 + (size_t)ubase * 4096);
    int nchunk = ntile * 2;                  // 4 KB chunks
    for (int it = 0; it < nchunk; ++it) {
      int off = (it << 12) + (w << 10);
      gl_lds16(wsrc + off + lane * 16, lds + off);
    }
    const char* xsrc = (const char*)(xnb + (size_t)m0tok * 512);
    for (int it = w; it < 14; it += 4) {
      int i = it * 64 + lane;
      int isw = i ^ ((i >> 3) & 7);
      gl_lds16(xsrc + isw * 16, lds + 114688 + it * 1024);
    }
    for (int it = w; it < 13; it += 4) {
      int i = it * 64 + lane;
      if (i > 783) i = 783;
      int qq = i / 56, rm = i - qq * 56;
      gl_lds16((const char*)(attnp + ((size_t)(nq0 + qq) * NTOK + m0tok) * 16) + rm * 16,
               lds + 129024 + it * 1024);
    }
    __syncthreads();

    const float* attL = (const float*)(lds + 129024);
    f32x4 acc[4][4];
    #pragma unroll
    for (int qi = 0; qi < 4; ++qi)
      #pragma unroll
      for (int tt = 0; tt < 4; ++tt) acc[qi][tt] = (f32x4)0.0f;
    int mynq = (w < 2) ? 4 : 3;

    #pragma unroll
    for (int qi = 0; qi < 4; ++qi) {
      if (qi < mynq) {
        int yq = w + 4 * qi;                 // interleaved for balance
        int lo = dh ? 0 : yq;
        int hi = dh ? yq - 1 : 13;
        for (int ym = lo; ym <= hi; ++ym) {
          int slot = dh ? (yq - ym - 1) : (yq - ym + 13);
          const char* wb = lds + slot * 8192 + lane * 16;
          U4S8 B0a, B0b, B1a, B1b, B2a, B2b, B3a, B3b;
          B0a.u4 = *(const uint4*)(wb);
          B0b.u4 = *(const uint4*)(wb + 1024);
          B1a.u4 = *(const uint4*)(wb + 2048);
          B1b.u4 = *(const uint4*)(wb + 3072);
          B2a.u4 = *(const uint4*)(wb + 4096);
          B2b.u4 = *(const uint4*)(wb + 5120);
          B3a.u4 = *(const uint4*)(wb + 6144);
          B3b.u4 = *(const uint4*)(wb + 7168);
          int o0 = ym * 1024 + b * 128 + 16 * g;
          uint4 xv0 = *(const uint4*)(lds + 114688 + (o0 ^ (b << 4)));
          uint4 xv1 = *(const uint4*)(lds + 114688 + ((o0 + 64) ^ (b << 4)));
          float av = attL[(yq * 14 + ym) * 16 + r];
          U4S8 a0, a1;
          #pragma unroll
          for (int qd = 0; qd < 4; ++qd) {
            a0.u[qd] = mulpack(((const unsigned*)&xv0)[qd], av);
            a1.u[qd] = mulpack(((const unsigned*)&xv1)[qd], av);
          }
          acc[qi][0] = MFMA(a0.s, B0a.s, acc[qi][0], 0, 0, 0);
          acc[qi][0] = MFMA(a1.s, B0b.s, acc[qi][0], 0, 0, 0);
          acc[qi][1] = MFMA(a0.s, B1a.s, acc[qi][1], 0, 0, 0);
          acc[qi][1] = MFMA(a1.s, B1b.s, acc[qi][1], 0, 0, 0);
          acc[qi][2] = MFMA(a0.s, B2a.s, acc[qi][2], 0, 0, 0);
          acc[qi][2] = MFMA(a1.s, B2b.s, acc[qi][2], 0, 0, 0);
          acc[qi][3] = MFMA(a0.s, B3a.s, acc[qi][3], 0, 0, 0);
          acc[qi][3] = MFMA(a1.s, B3b.s, acc[qi][3], 0, 0, 0);
        }
      }
    }
    // ---- epilogue: valid-half stores to part slot ----
    int slotg = xm * 2 + dh;
    int th = g >> 1;
    #pragma unroll
    for (int qi = 0; qi < 4; ++qi) {
      if (qi < mynq) {
        int n = nq0 + w + 4 * qi;
        float* pb = part + ((size_t)(slotg * NTOK + n) * 16) * 32;
        #pragma unroll
        for (int reg = 0; reg < 4; ++reg) {
          int row = 4 * g + reg;
          pb[row * 32 + r]      = acc[qi][2 * th][reg];
          pb[row * 32 + 16 + r] = acc[qi][2 * th + 1][reg];
        }
      }
    }
    return;
  }

  if (bid < 400) {
    // ---- CLS query row: n = 0, all m; u = 729 + m ----
    int j = bid - 392;
    int ws = j * 4 + w;
    f32x4 acc[4];
    #pragma unroll
    for (int tt = 0; tt < 4; ++tt) acc[tt] = (f32x4)0.0f;
    for (int m = ws; m < NTOK; m += 32) {
      const unsigned short* wp = wt2 + (size_t)(729 + m) * 4096 + lane * 8;
      U4S8 B0a, B0b, B1a, B1b, B2a, B2b, B3a, B3b;
      B0a.s = *(const bf16x8*)(wp);
      B0b.s = *(const bf16x8*)(wp + 512);
      B1a.s = *(const bf16x8*)(wp + 1024);
      B1b.s = *(const bf16x8*)(wp + 1536);
      B2a.s = *(const bf16x8*)(wp + 2048);
      B2b.s = *(const bf16x8*)(wp + 2560);
      B3a.s = *(const bf16x8*)(wp + 3072);
      B3b.s = *(const bf16x8*)(wp + 3584);
      const unsigned short* xp = xnb + (size_t)m * 512 + b * 64 + 8 * g;
      uint4 xv0 = *(const uint4*)(xp);
      uint4 xv1 = *(const uint4*)(xp + 32);  // FIX: +32 ushorts = +64 B (d in [32,64))
      float av = attnp[(size_t)m * 16 + r];
      U4S8 a0, a1;
      #pragma unroll
      for (int qd = 0; qd < 4; ++qd) {
        a0.u[qd] = mulpack(((const unsigned*)&xv0)[qd], av);
        a1.u[qd] = mulpack(((const unsigned*)&xv1)[qd], av);
      }
      acc[0] = MFMA(a0.s, B0a.s, acc[0], 0, 0, 0);
      acc[0] = MFMA(a1.s, B0b.s, acc[0], 0, 0, 0);
      acc[1] = MFMA(a0.s, B1a.s, acc[1], 0, 0, 0);
      acc[1] = MFMA(a1.s, B1b.s, acc[1], 0, 0, 0);
      acc[2] = MFMA(a0.s, B2a.s, acc[2], 0, 0, 0);
      acc[2] = MFMA(a1.s, B2b.s, acc[2], 0, 0, 0);
      acc[3] = MFMA(a0.s, B3a.s, acc[3], 0, 0, 0);
      acc[3] = MFMA(a1.s, B3b.s, acc[3], 0, 0, 0);
    }
    float* pb = (float*)lds;
    int th = g >> 1;
    #pragma unroll
    for (int reg = 0; reg < 4; ++reg) {
      int row = 4 * g + reg;
      pb[w * 512 + row * 32 + r]      = acc[2 * th][reg];
      pb[w * 512 + row * 32 + 16 + r] = acc[2 * th + 1][reg];
    }
    __syncthreads();
    for (int i = t; i < 512; i += 256)
      cls_part[j * 512 + i] = (pb[i] + pb[512 + i]) + (pb[1024 + i] + pb[1536 + i]);
    return;
  }

  // ---- m = 0 column (n >= 1): u = 925 + n; slot 28 ----
  {
    int xq = bid - 400;
    int nq0 = 1 + 14 * xq;
    int mynq = (w < 2) ? 4 : 3;
    int th = g >> 1;
    const unsigned short* xp = xnb + b * 64 + 8 * g;  // token 0
    uint4 xv0 = *(const uint4*)(xp);
    uint4 xv1 = *(const uint4*)(xp + 32);  // FIX: +32 ushorts = +64 B (d in [32,64))
    #pragma unroll
    for (int qi = 0; qi < 4; ++qi) {
      if (qi < mynq) {
        int n = nq0 + w + 4 * qi;
        const unsigned short* wp = wt2 + (size_t)(925 + n) * 4096 + lane * 8;
        U4S8 B0a, B0b, B1a, B1b, B2a, B2b, B3a, B3b;
        B0a.s = *(const bf16x8*)(wp);
        B0b.s = *(const bf16x8*)(wp + 512);
        B1a.s = *(const bf16x8*)(wp + 1024);
        B1b.s = *(const bf16x8*)(wp + 1536);
        B2a.s = *(const bf16x8*)(wp + 2048);
        B2b.s = *(const bf16x8*)(wp + 2560);
        B3a.s = *(const bf16x8*)(wp + 3072);
        B3b.s = *(const bf16x8*)(wp + 3584);
        float av = attnp[(size_t)n * NTOK * 16 + r];
        U4S8 a0, a1;
        f32x4 acc[4];
        #pragma unroll
        for (int tt = 0; tt < 4; ++tt) acc[tt] = (f32x4)0.0f;
        #pragma unroll
        for (int qd = 0; qd < 4; ++qd) {
          a0.u[qd] = mulpack(((const unsigned*)&xv0)[qd], av);
          a1.u[qd] = mulpack(((const unsigned*)&xv1)[qd], av);
        }
        acc[0] = MFMA(a0.s, B0a.s, acc[0], 0, 0, 0);
        acc[0] = MFMA(a1.s, B0b.s, acc[0], 0, 0, 0);
        acc[1] = MFMA(a0.s, B1a.s, acc[1], 0, 0, 0);
        acc[1] = MFMA(a1.s, B1b.s, acc[1], 0, 0, 0);
        acc[2] = MFMA(a0.s, B2a.s, acc[2], 0, 0, 0);
        acc[2] = MFMA(a1.s, B2b.s, acc[2], 0, 0, 0);
        acc[3] = MFMA(a0.s, B3a.s, acc[3], 0, 0, 0);
        acc[3] = MFMA(a1.s, B3b.s, acc[3], 0, 0, 0);
        float* pb = part + ((size_t)(28 * NTOK + n) * 16) * 32;
        #pragma unroll
        for (int reg = 0; reg < 4; ++reg) {
          int row = 4 * g + reg;
          pb[row * 32 + r]      = acc[2 * th][reg];
          pb[row * 32 + 16 + r] = acc[2 * th + 1][reg];
        }
      }
    }
  }
}

// ---------------------------------------------------------------------------
// Kernel 4: combine part slots + output projection + bias. block per n.
// ---------------------------------------------------------------------------
__global__ __launch_bounds__(256) void k4_out(
    const float* __restrict__ part, const float* __restrict__ cls_part,
    const float* __restrict__ wout, const float* __restrict__ bout,
    float* __restrict__ out) {
  int n = blockIdx.x, t = threadIdx.x;
  int ro = t >> 4, es = t & 15;
  int h = ro >> 3, bb = ro & 7;
  float s0 = 0.f, s1 = 0.f;
  if (n == 0) {
    #pragma unroll
    for (int sl = 0; sl < 8; ++sl) {
      float2 v = *(const float2*)(cls_part + sl * 512 + ro * 32 + es * 2);
      s0 += v.x; s1 += v.y;
    }
  } else {
    #pragma unroll
    for (int sl = 0; sl < 29; ++sl) {
      float2 v = *(const float2*)(part + ((size_t)(sl * NTOK + n) * 16 + ro) * 32 + es * 2);
      s0 += v.x; s1 += v.y;
    }
  }
  __shared__ float is[512];
  is[bb * 64 + h * 32 + es * 2]     = s0;
  is[bb * 64 + h * 32 + es * 2 + 1] = s1;
  __syncthreads();
  #pragma unroll
  for (int idx = t; idx < 512; idx += 256) {
    int b2 = idx >> 6, d = idx & 63;
    float o = bout[d];
    const float* ir = is + b2 * 64;
    #pragma unroll 8
    for (int e = 0; e < 64; ++e)
      o = fmaf(ir[e], wout[e * 64 + d], o);
    out[((size_t)b2 * NTOK + n) * 64 + d] = o;
  }
}

// ---------------------------------------------------------------------------
extern "C" void kernel_launch(void* const* d_in, const int* in_sizes, int n_in,
                              void* d_out, int out_size, void* d_ws, size_t ws_size,
                              hipStream_t stream) {
  const float* x     = (const float*)d_in[0];
  const float* gamma = (const float*)d_in[1];
  const float* beta  = (const float*)d_in[2];
  const float* wqk   = (const float*)d_in[3];
  const float* up    = (const float*)d_in[4];
  const float* wout  = (const float*)d_in[5];
  const float* bout  = (const float*)d_in[6];
  float* out = (float*)d_out;

  int NU = in_sizes[4] / 4096;     // 1122

  char* w8 = (char*)d_ws;
  unsigned short* wt2 = (unsigned short*)w8;              // 9,191,424
  unsigned short* xnb = (unsigned short*)(w8 + 9191424);  //   201,728
  float* q    = (float*)(w8 + 9393152);                   //   403,456
  float* kk   = (float*)(w8 + 9796608);                   //   403,456
  float* attn = (float*)(w8 + 10200064);                  // 2,483,776
  float* part = (float*)(w8 + 12683840);                  // 29*197*2048 = 11,700,224
  float* clsp = (float*)(w8 + 24384064);                  //    16,384

  hipFuncSetAttribute((const void*)k3_main,
                      hipFuncAttributeMaxDynamicSharedMemorySize, DYNLDS);

  kA      <<<NU + 394, 256, 0, stream>>>(up, x, gamma, beta, wqk, wt2, xnb, q, kk, NU);
  k2_attn <<<256,      256, 0, stream>>>(q, kk, attn);
  k3_main <<<414,      256, DYNLDS, stream>>>(xnb, attn, wt2, part, clsp);
  k4_out  <<<NTOK,     256, 0, stream>>>(part, clsp, wout, bout, out);
}